// Round 6
// baseline (2751.226 us; speedup 1.0000x reference)
//
#include <hip/hip_runtime.h>

// LSTM (B=256, T=256, F=128, H=1024) + sigmoid + FC(1024->128).
// Persistent 256-WG kernel. Per step t:
//   gates[B,4H] = [h_t | x_t] (fp16) x W_cat^T (fp16, register-resident) + bias
//   per-lane i,f,g,o -> c,h update (fp32).
// h exchange (R6): producers store write-through to the coherence point (MALL)
// with AGENT-scope relaxed atomic stores (sc0 sc1, no dirty L2 lines).
// Consumers issue ONE agent-scope acquire fence per wave per step (lowers to
// s_waitcnt + buffer_inv sc1 - the compiler's own agent-acquire lowering),
// then read h with PLAIN CACHED loads: first toucher refills the line from
// MALL into the XCD L2; the cohort's other WGs on that XCD hit L2 (~200cy).
// This removes the 32x-redundant MALL-bypass reads of R5 (16 MB/step -> ~4).
// Barrier (RMW-free, from R5): cohort rg has 32 epoch flags on ONE 128B line.
// Arrival = tid0 sc0sc1-stores t+1 to flags[cg]; poll = wave 0 lanes 0..31
// load all 32 flags coalesced, __all(flag >= t+1). Monotonic, replay-safe.
//
// Tiling: WG (rg=wg>>5, cg=wg&31) owns batch rows rg*32..+31 and h-cols
// cg*32..+31 (gate cols n*1024+cg*32+0..31, n=0..3). 4 waves split K uniformly:
// wave w owns h-K [w*256,+256) (16 chunks) + x-K [w*32,+32) (2 chunks).
// Cross-wave reduction in 64KB LDS. MFMA mfma_f32_32x32x16_f16, C layout:
// col=lane&31, row=(reg&3)+8*(reg>>2)+4*(lane>>5) [m101].

typedef _Float16 f16x8 __attribute__((ext_vector_type(8)));
typedef float f32x16 __attribute__((ext_vector_type(16)));
typedef unsigned long long u64;

#define SCOPE_AGENT __HIP_MEMORY_SCOPE_AGENT

#define WS_WP    0ull
#define WS_BIAS  9437184ull
#define WS_XT    (WS_BIAS + 16384ull)
#define WS_HB0   (WS_XT + 16777216ull)
#define WS_HB1   (WS_HB0 + 524288ull)
#define WS_SIGH  (WS_HB1 + 524288ull)
#define WS_BAR   (WS_SIGH + 1048576ull)

__device__ __forceinline__ unsigned short f2h(float f) {
  _Float16 h = (_Float16)f;
  return __builtin_bit_cast(unsigned short, h);
}

__device__ __forceinline__ float fast_sig(float x) {
  return __builtin_amdgcn_rcpf(1.f + __expf(-x));
}
__device__ __forceinline__ float fast_tanh(float x) {
  // tanh(x) = 2*sigmoid(2x) - 1 ; exp overflow -> rcp(inf)=0 -> -1 (correct)
  return __builtin_fmaf(2.f, fast_sig(2.f * x), -1.f);
}

// Pack W_cat[4096][1152] (fp16) into per-(cg,wave,n,q,lane) MFMA B-fragments.
// flat idx i = ((((cg*4 + w)*4 + n)*18 + q)*64 + l)*8 + j
//   gcol = n*1024 + cg*32 + (l&31)
//   q<16:  k = w*256 + q*16 + (l>>5)*8 + j          (h region, W_hh[gcol][k])
//   q>=16: f = w*32 + (q-16)*16 + (l>>5)*8 + j      (x region, W_ih[gcol][f])
__global__ void prep_pack(const float* __restrict__ W_ih, const float* __restrict__ W_hh,
                          const float* __restrict__ b_ih, const float* __restrict__ b_hh,
                          unsigned short* __restrict__ wp, float* __restrict__ bias) {
  unsigned i = blockIdx.x * 256u + threadIdx.x;
  if (i < 4718592u) {
    unsigned j = i & 7u;
    unsigned l = (i >> 3) & 63u;
    unsigned rest = i >> 9;
    unsigned q = rest % 18u;
    unsigned rest2 = rest / 18u;
    unsigned n = rest2 & 3u;
    unsigned rest3 = rest2 >> 2;
    unsigned w = rest3 & 3u;
    unsigned cg = rest3 >> 2;
    unsigned gcol = n * 1024u + cg * 32u + (l & 31u);
    unsigned khi = (l >> 5) * 8u + j;
    float v;
    if (q < 16u) {
      unsigned k = w * 256u + q * 16u + khi;
      v = W_hh[(size_t)gcol * 1024u + k];
    } else {
      unsigned k = w * 32u + (q - 16u) * 16u + khi;
      v = W_ih[(size_t)gcol * 128u + k];
    }
    wp[i] = f2h(v);
  }
  if (i < 4096u) bias[i] = b_ih[i] + b_hh[i];
}

// x[B][T][F] fp32 -> xT[T][B][F] fp16 ; h0 -> fp16 hb0 ; zero barrier words.
__global__ void prep_misc(const float* __restrict__ x, const float* __restrict__ h0,
                          unsigned short* __restrict__ xT, unsigned short* __restrict__ hb0,
                          unsigned* __restrict__ bar) {
  unsigned i = blockIdx.x * 256u + threadIdx.x;
  if (i < 8388608u) {
    unsigned f = i & 127u;
    unsigned b = (i >> 7) & 255u;
    unsigned t = i >> 15;
    xT[i] = f2h(x[((size_t)b * 256u + t) * 128u + f]);
  }
  if (i < 262144u) hb0[i] = f2h(h0[i]);
  if (i < 768u) bar[i] = 0u;
}

__launch_bounds__(256, 1)
__global__ void lstm_main(const unsigned short* __restrict__ wp,
                          const float* __restrict__ bias,
                          const unsigned short* __restrict__ xT,
                          unsigned short* __restrict__ hb0,
                          unsigned short* __restrict__ hb1,
                          const float* __restrict__ c0,
                          float* __restrict__ sigh,
                          unsigned* __restrict__ bar) {
  extern __shared__ char lds[];
  float4* redv = (float4*)lds;                            // 64 KB reduce buffer
  unsigned short* hst = (unsigned short*)(lds + 65536);   // 2 KB h staging tile

  const unsigned tid = threadIdx.x;
  const unsigned wg  = blockIdx.x;
  const unsigned w   = tid >> 6;       // wave 0..3 (K-part)
  const unsigned l   = tid & 63u;
  const unsigned rg  = wg >> 5;        // 0..7  batch row group (32 rows) = cohort
  const unsigned cg  = wg & 31u;       // 0..31 h-col group (32 cols)
  const unsigned lo5 = l & 31u;
  const unsigned hi  = l >> 5;

  // ---- register-resident W fragments (72 x int4 = 288 VGPRs) ----
  int4 Braw[4][18];
  {
    const int4* wpv = (const int4*)wp;
    const unsigned wbase = (cg * 4u + w) * 4608u;  // 4*18*64 int4 per (cg,w)
#pragma unroll
    for (int n = 0; n < 4; ++n) {
#pragma unroll
      for (int q = 0; q < 18; ++q) {
        Braw[n][q] = wpv[wbase + (unsigned)(n * 18 + q) * 64u + l];
      }
    }
  }

  float bias_v[4];
#pragma unroll
  for (int n = 0; n < 4; ++n) bias_v[n] = bias[(unsigned)n * 1024u + cg * 32u + lo5];

  // c state + output offsets: rows r = rg*32 + 8w + i + 4*hi, col = cg*32 + lo5
  const unsigned col = cg * 32u + lo5;
  float c_st[4];
  unsigned soff[4];
#pragma unroll
  for (int i = 0; i < 4; ++i) {
    unsigned r = rg * 32u + 8u * w + (unsigned)i + 4u * hi;
    soff[i] = r * 1024u + col;
    c_st[i] = c0[soff[i]];
  }

  // A-operand addressing: row = rg*32 + lo5
  //   h chunks q=0..15: k = w*256 + q*16 + hi*8 + j
  //   x chunks q=16,17: f = w*32 + (q-16)*16 + hi*8 + j
  const unsigned arow = rg * 32u + lo5;
  const unsigned hbyte = (arow * 1024u + w * 256u + hi * 8u) * 2u;
  unsigned xb = (arow * 128u + w * 32u + hi * 8u) * 2u;  // + 65536/step

  const char* hrd = (const char*)hb0;
  char* hwr = (char*)hb1;
  const char* xbase = (const char*)xT;
  unsigned* flags = &bar[rg * 32u];    // 32 x 4B epoch flags, one 128B line

  // h store-out addressing (after LDS staging): 256 threads x 8B
  const unsigned srow = tid >> 3;      // 0..31 local row
  const unsigned sseg = tid & 7u;      // 0..7  4-col segment
  const unsigned sgoff = (((rg * 32u + srow) * 1024u) + cg * 32u + sseg * 4u) * 2u;

  // prefetch x fragments for t=0 (plain cached loads)
  int4 xr[2];
  xr[0] = *(const int4*)(xbase + xb);
  xr[1] = *(const int4*)(xbase + xb + 32u);

  for (unsigned t = 0; t < 256u; ++t) {
    // ---- agent-acquire: s_waitcnt + buffer_inv sc1 (per wave, once/step) ----
    // Makes the producers' MALL-resident h stores visible to PLAIN loads;
    // first load refills the XCD L2, cohort-mates on this XCD then hit L2.
    __builtin_amdgcn_fence(__ATOMIC_ACQUIRE, "agent");

    // ---- 16 h fragment loads (plain cached; L2-shared across cohort) ----
    int4 ah[16];
#pragma unroll
    for (int q = 0; q < 16; ++q)
      ah[q] = *(const int4*)(hrd + hbyte + (unsigned)q * 32u);

    f32x16 acc[4] = {};
    // x chunks first: registers already resident, overlap h-load latency
#pragma unroll
    for (int qx = 0; qx < 2; ++qx) {
      f16x8 a = __builtin_bit_cast(f16x8, xr[qx]);
      acc[0] = __builtin_amdgcn_mfma_f32_32x32x16_f16(a, __builtin_bit_cast(f16x8, Braw[0][16 + qx]), acc[0], 0, 0, 0);
      acc[1] = __builtin_amdgcn_mfma_f32_32x32x16_f16(a, __builtin_bit_cast(f16x8, Braw[1][16 + qx]), acc[1], 0, 0, 0);
      acc[2] = __builtin_amdgcn_mfma_f32_32x32x16_f16(a, __builtin_bit_cast(f16x8, Braw[2][16 + qx]), acc[2], 0, 0, 0);
      acc[3] = __builtin_amdgcn_mfma_f32_32x32x16_f16(a, __builtin_bit_cast(f16x8, Braw[3][16 + qx]), acc[3], 0, 0, 0);
    }
#pragma unroll
    for (int q = 0; q < 16; ++q) {
      f16x8 a = __builtin_bit_cast(f16x8, ah[q]);
      acc[0] = __builtin_amdgcn_mfma_f32_32x32x16_f16(a, __builtin_bit_cast(f16x8, Braw[0][q]), acc[0], 0, 0, 0);
      acc[1] = __builtin_amdgcn_mfma_f32_32x32x16_f16(a, __builtin_bit_cast(f16x8, Braw[1][q]), acc[1], 0, 0, 0);
      acc[2] = __builtin_amdgcn_mfma_f32_32x32x16_f16(a, __builtin_bit_cast(f16x8, Braw[2][q]), acc[2], 0, 0, 0);
      acc[3] = __builtin_amdgcn_mfma_f32_32x32x16_f16(a, __builtin_bit_cast(f16x8, Braw[3][q]), acc[3], 0, 0, 0);
    }

    // ---- cross-wave K reduction via LDS ----
#pragma unroll
    for (int n = 0; n < 4; ++n) {
#pragma unroll
      for (int c = 0; c < 4; ++c) {
        float4 v;
        v.x = acc[n][4 * c + 0]; v.y = acc[n][4 * c + 1];
        v.z = acc[n][4 * c + 2]; v.w = acc[n][4 * c + 3];
        redv[((w * 4u + (unsigned)n) * 4u + (unsigned)c) * 64u + l] = v;
      }
    }
    __syncthreads();

    float gv[4][4];
#pragma unroll
    for (int n = 0; n < 4; ++n) {
      float4 s; s.x = bias_v[n]; s.y = bias_v[n]; s.z = bias_v[n]; s.w = bias_v[n];
#pragma unroll
      for (int wo = 0; wo < 4; ++wo) {
        float4 v = redv[(((unsigned)wo * 4u + (unsigned)n) * 4u + w) * 64u + l];
        s.x += v.x; s.y += v.y; s.z += v.z; s.w += v.w;
      }
      gv[n][0] = s.x; gv[n][1] = s.y; gv[n][2] = s.z; gv[n][3] = s.w;
    }

    // ---- per-lane LSTM cell update (rows 8w+i+4hi); stage h to LDS ----
    const bool last = (t == 255u);
#pragma unroll
    for (int i = 0; i < 4; ++i) {
      float ig = fast_sig(gv[0][i]);
      float fg = fast_sig(gv[1][i]);
      float gg = fast_tanh(gv[2][i]);
      float og = fast_sig(gv[3][i]);
      float cc = fg * c_st[i] + ig * gg;
      c_st[i] = cc;
      float hh = og * fast_tanh(cc);
      hst[(8u * w + (unsigned)i + 4u * hi) * 32u + lo5] = f2h(hh);
      if (last) sigh[soff[i]] = fast_sig(hh);
    }

    if (!last) {
      __syncthreads();  // h staging tile complete
      // ---- coalesced 8B agent-coherent h store-out (write-through) ----
      {
        u64 v = *(const u64*)(hst + srow * 32u + sseg * 4u);
        __hip_atomic_store((u64*)(hwr + sgoff), v, __ATOMIC_RELAXED, SCOPE_AGENT);
      }
      // prefetch next step's x fragments (independent of h; hides under drain)
      xb += 65536u;
      xr[0] = *(const int4*)(xbase + xb);
      xr[1] = *(const int4*)(xbase + xb + 32u);
      // __syncthreads lowering waits vmcnt(0): every thread's h store is ACKed
      // at the coherence point before any thread proceeds to the flag store.
      __syncthreads();
      // ---- RMW-free epoch-flag barrier ----
      if (tid == 0)
        __hip_atomic_store(&flags[cg], t + 1u, __ATOMIC_RELAXED, SCOPE_AGENT);
      if (tid < 64u) {
        const unsigned tgt = t + 1u;
        for (;;) {
          unsigned f = __hip_atomic_load(&flags[l & 31u], __ATOMIC_RELAXED, SCOPE_AGENT);
          if (__all(f >= tgt)) break;
          __builtin_amdgcn_s_sleep(1);
        }
      }
      __syncthreads();
    }

    const char* tmp = hrd; hrd = hwr; hwr = (char*)tmp;
  }
}

// out[b][o] = b_fc[o] + sum_k sigh[b][k] * W_fc[o][k]
__global__ void final_fc(const float* __restrict__ sigh, const float* __restrict__ W_fc,
                         const float* __restrict__ b_fc, float* __restrict__ out) {
  unsigned b = blockIdx.x;
  unsigned o = threadIdx.x;
  const float* hrow = sigh + (size_t)b * 1024u;
  const float* wrow = W_fc + (size_t)o * 1024u;
  float acc = b_fc[o];
#pragma unroll 8
  for (unsigned k = 0; k < 1024u; k += 4u) {
    float4 hv = *(const float4*)(hrow + k);
    float4 wv = *(const float4*)(wrow + k);
    acc += hv.x * wv.x + hv.y * wv.y + hv.z * wv.z + hv.w * wv.w;
  }
  out[b * 128u + o] = acc;
}

extern "C" void kernel_launch(void* const* d_in, const int* in_sizes, int n_in,
                              void* d_out, int out_size, void* d_ws, size_t ws_size,
                              hipStream_t stream) {
  (void)in_sizes; (void)n_in; (void)out_size; (void)ws_size;
  const float* x    = (const float*)d_in[0];
  const float* h0   = (const float*)d_in[1];
  const float* c0   = (const float*)d_in[2];
  const float* W_ih = (const float*)d_in[3];
  const float* W_hh = (const float*)d_in[4];
  const float* b_ih = (const float*)d_in[5];
  const float* b_hh = (const float*)d_in[6];
  const float* W_fc = (const float*)d_in[7];
  const float* b_fc = (const float*)d_in[8];

  char* ws = (char*)d_ws;
  unsigned short* wp   = (unsigned short*)(ws + WS_WP);
  float*          bias = (float*)(ws + WS_BIAS);
  unsigned short* xT   = (unsigned short*)(ws + WS_XT);
  unsigned short* hb0  = (unsigned short*)(ws + WS_HB0);
  unsigned short* hb1  = (unsigned short*)(ws + WS_HB1);
  float*          sigh = (float*)(ws + WS_SIGH);
  unsigned*       bar  = (unsigned*)(ws + WS_BAR);
  float*          out  = (float*)d_out;

  prep_pack<<<18432, 256, 0, stream>>>(W_ih, W_hh, b_ih, b_hh, wp, bias);
  prep_misc<<<32768, 256, 0, stream>>>(x, h0, xT, hb0, bar);
  lstm_main<<<256, 256, 67584, stream>>>(wp, bias, xT, hb0, hb1, c0, sigh, bar);
  final_fc<<<256, 128, 0, stream>>>(sigh, W_fc, b_fc, out);
}

// Round 7
// 1313.744 us; speedup vs baseline: 2.0942x; 2.0942x over previous
//
#include <hip/hip_runtime.h>

// LSTM (B=256, T=256, F=128, H=1024) + sigmoid + FC(1024->128).
// Persistent 256-WG kernel. Per step t:
//   gates[B,4H] = [h_t | x_t] (fp16) x W_cat^T (fp16, register-resident) + bias
//   per-lane i,f,g,o -> c,h update (fp32).
// R7 h exchange: producers write-through to the coherence point (MALL) with
// AGENT-scope relaxed atomic 8B stores (proven R3/R5). Consumers COALESCE:
// each WG loads its 64KB h row-tile LINEARLY (thread tid: 16B @ tile + r*4096
// + tid*16, u64-pair agent-scope bypass loads -> 8x128B coalesced MALL
// requests per instruction, ~128 requests/WG/step vs ~2000 scattered in R5),
// stages it into LDS with a row-XOR swizzle (byte ^= ((row&7)<<4)), then MFMA
// A-fragments come from ds_read_b128 (4-way conflict, hidden under MFMA).
// The 64KB LDS buffer is time-shared: h-stage -> frag reads -> sync ->
// cross-wave reduce overwrites it. NO cache-wide maintenance ops anywhere
// (R6's agent-acquire fence = buffer_inv sc1 per wave per step regressed 40%).
// Barrier (RMW-free, R5): cohort rg has 32 epoch flags on ONE 128B line;
// arrival = tid0 stores t+1 to flags[cg]; poll = wave0 lanes 0..31 coalesced
// load + __all(flag >= t+1). Monotonic, replay-safe.
//
// Tiling: WG (rg=wg>>5, cg=wg&31) owns batch rows rg*32..+31 and h-cols
// cg*32..+31 (gate cols n*1024+cg*32+0..31, n=0..3). 4 waves split K:
// wave w owns h-K [w*256,+256) (16 chunks) + x-K [w*32,+32) (2 chunks).
// MFMA mfma_f32_32x32x16_f16, C layout: col=lane&31,
// row=(reg&3)+8*(reg>>2)+4*(lane>>5) [m101].

typedef _Float16 f16x8 __attribute__((ext_vector_type(8)));
typedef float f32x16 __attribute__((ext_vector_type(16)));
typedef unsigned long long u64;

#define SCOPE_AGENT __HIP_MEMORY_SCOPE_AGENT

#define WS_WP    0ull
#define WS_BIAS  9437184ull
#define WS_XT    (WS_BIAS + 16384ull)
#define WS_HB0   (WS_XT + 16777216ull)
#define WS_HB1   (WS_HB0 + 524288ull)
#define WS_SIGH  (WS_HB1 + 524288ull)
#define WS_BAR   (WS_SIGH + 1048576ull)

__device__ __forceinline__ unsigned short f2h(float f) {
  _Float16 h = (_Float16)f;
  return __builtin_bit_cast(unsigned short, h);
}

__device__ __forceinline__ float fast_sig(float x) {
  return __builtin_amdgcn_rcpf(1.f + __expf(-x));
}
__device__ __forceinline__ float fast_tanh(float x) {
  // tanh(x) = 2*sigmoid(2x) - 1 ; exp overflow -> rcp(inf)=0 -> -1 (correct)
  return __builtin_fmaf(2.f, fast_sig(2.f * x), -1.f);
}

// Pack W_cat[4096][1152] (fp16) into per-(cg,wave,n,q,lane) MFMA B-fragments.
// flat idx i = ((((cg*4 + w)*4 + n)*18 + q)*64 + l)*8 + j
//   gcol = n*1024 + cg*32 + (l&31)
//   q<16:  k = w*256 + q*16 + (l>>5)*8 + j          (h region, W_hh[gcol][k])
//   q>=16: f = w*32 + (q-16)*16 + (l>>5)*8 + j      (x region, W_ih[gcol][f])
__global__ void prep_pack(const float* __restrict__ W_ih, const float* __restrict__ W_hh,
                          const float* __restrict__ b_ih, const float* __restrict__ b_hh,
                          unsigned short* __restrict__ wp, float* __restrict__ bias) {
  unsigned i = blockIdx.x * 256u + threadIdx.x;
  if (i < 4718592u) {
    unsigned j = i & 7u;
    unsigned l = (i >> 3) & 63u;
    unsigned rest = i >> 9;
    unsigned q = rest % 18u;
    unsigned rest2 = rest / 18u;
    unsigned n = rest2 & 3u;
    unsigned rest3 = rest2 >> 2;
    unsigned w = rest3 & 3u;
    unsigned cg = rest3 >> 2;
    unsigned gcol = n * 1024u + cg * 32u + (l & 31u);
    unsigned khi = (l >> 5) * 8u + j;
    float v;
    if (q < 16u) {
      unsigned k = w * 256u + q * 16u + khi;
      v = W_hh[(size_t)gcol * 1024u + k];
    } else {
      unsigned k = w * 32u + (q - 16u) * 16u + khi;
      v = W_ih[(size_t)gcol * 128u + k];
    }
    wp[i] = f2h(v);
  }
  if (i < 4096u) bias[i] = b_ih[i] + b_hh[i];
}

// x[B][T][F] fp32 -> xT[T][B][F] fp16 ; h0 -> fp16 hb0 ; zero barrier words.
__global__ void prep_misc(const float* __restrict__ x, const float* __restrict__ h0,
                          unsigned short* __restrict__ xT, unsigned short* __restrict__ hb0,
                          unsigned* __restrict__ bar) {
  unsigned i = blockIdx.x * 256u + threadIdx.x;
  if (i < 8388608u) {
    unsigned f = i & 127u;
    unsigned b = (i >> 7) & 255u;
    unsigned t = i >> 15;
    xT[i] = f2h(x[((size_t)b * 256u + t) * 128u + f]);
  }
  if (i < 262144u) hb0[i] = f2h(h0[i]);
  if (i < 768u) bar[i] = 0u;
}

__launch_bounds__(256, 1)
__global__ void lstm_main(const unsigned short* __restrict__ wp,
                          const float* __restrict__ bias,
                          const unsigned short* __restrict__ xT,
                          unsigned short* __restrict__ hb0,
                          unsigned short* __restrict__ hb1,
                          const float* __restrict__ c0,
                          float* __restrict__ sigh,
                          unsigned* __restrict__ bar) {
  extern __shared__ char lds[];
  // lds[0..65536): time-shared h-stage buffer / cross-wave reduce buffer
  float4* redv = (float4*)lds;
  unsigned short* hst = (unsigned short*)(lds + 65536);   // 2 KB h staging tile

  const unsigned tid = threadIdx.x;
  const unsigned wg  = blockIdx.x;
  const unsigned w   = tid >> 6;       // wave 0..3 (K-part)
  const unsigned l   = tid & 63u;
  const unsigned rg  = wg >> 5;        // 0..7  batch row group (32 rows) = cohort
  const unsigned cg  = wg & 31u;       // 0..31 h-col group (32 cols)
  const unsigned lo5 = l & 31u;
  const unsigned hi  = l >> 5;

  // ---- register-resident W fragments (72 x int4 = 288 VGPRs) ----
  int4 Braw[4][18];
  {
    const int4* wpv = (const int4*)wp;
    const unsigned wbase = (cg * 4u + w) * 4608u;  // 4*18*64 int4 per (cg,w)
#pragma unroll
    for (int n = 0; n < 4; ++n) {
#pragma unroll
      for (int q = 0; q < 18; ++q) {
        Braw[n][q] = wpv[wbase + (unsigned)(n * 18 + q) * 64u + l];
      }
    }
  }

  float bias_v[4];
#pragma unroll
  for (int n = 0; n < 4; ++n) bias_v[n] = bias[(unsigned)n * 1024u + cg * 32u + lo5];

  // c state + output offsets: rows r = rg*32 + 8w + i + 4*hi, col = cg*32 + lo5
  const unsigned col = cg * 32u + lo5;
  float c_st[4];
  unsigned soff[4];
#pragma unroll
  for (int i = 0; i < 4; ++i) {
    unsigned r = rg * 32u + 8u * w + (unsigned)i + 4u * hi;
    soff[i] = r * 1024u + col;
    c_st[i] = c0[soff[i]];
  }

  // LDS fragment-read addressing: lane l reads local row lo5,
  //   kbyte = w*512 + q*32 + hi*16; addr = (lo5*2048 + kbyte) ^ ((lo5&7)<<4)
  const unsigned fbase = lo5 * 2048u + w * 512u + hi * 16u;
  const unsigned fxor  = (lo5 & 7u) << 4;

  // staging addressing: thread tid stages 16B rounds r=0..15
  const unsigned sg16 = tid * 16u;               // byte within 4KB round block
  unsigned xb = ((rg * 32u + lo5) * 128u + w * 32u + hi * 8u) * 2u;  // xT byte, +65536/step

  const char* hrd = (const char*)hb0;
  char* hwr = (char*)hb1;
  const char* xbase = (const char*)xT;
  unsigned* flags = &bar[rg * 32u];    // 32 x 4B epoch flags, one 128B line
  const unsigned tilebase = rg * 65536u;  // 32 rows x 2048B

  // h store-out addressing (after LDS staging): 256 threads x 8B
  const unsigned srow = tid >> 3;      // 0..31 local row
  const unsigned sseg = tid & 7u;      // 0..7  4-col segment
  const unsigned sgoff = (((rg * 32u + srow) * 1024u) + cg * 32u + sseg * 4u) * 2u;

  // prefetch x fragments for t=0 (plain cached loads)
  int4 xr[2];
  xr[0] = *(const int4*)(xbase + xb);
  xr[1] = *(const int4*)(xbase + xb + 32u);

  for (unsigned t = 0; t < 256u; ++t) {
    // ---- coalesced agent-coherent staging loads: 64KB tile, 16 rounds ----
    u64 sa[16], sb[16];
#pragma unroll
    for (int r = 0; r < 16; ++r) {
      const char* src = hrd + tilebase + (unsigned)r * 4096u + sg16;
      sa[r] = __hip_atomic_load((const u64*)src,       __ATOMIC_RELAXED, SCOPE_AGENT);
      sb[r] = __hip_atomic_load((const u64*)(src + 8), __ATOMIC_RELAXED, SCOPE_AGENT);
    }

    f32x16 acc[4] = {};
    // x chunks while staging loads are in flight (registers already resident)
#pragma unroll
    for (int qx = 0; qx < 2; ++qx) {
      f16x8 a = __builtin_bit_cast(f16x8, xr[qx]);
      acc[0] = __builtin_amdgcn_mfma_f32_32x32x16_f16(a, __builtin_bit_cast(f16x8, Braw[0][16 + qx]), acc[0], 0, 0, 0);
      acc[1] = __builtin_amdgcn_mfma_f32_32x32x16_f16(a, __builtin_bit_cast(f16x8, Braw[1][16 + qx]), acc[1], 0, 0, 0);
      acc[2] = __builtin_amdgcn_mfma_f32_32x32x16_f16(a, __builtin_bit_cast(f16x8, Braw[2][16 + qx]), acc[2], 0, 0, 0);
      acc[3] = __builtin_amdgcn_mfma_f32_32x32x16_f16(a, __builtin_bit_cast(f16x8, Braw[3][16 + qx]), acc[3], 0, 0, 0);
    }

    // ---- write stage to LDS, row-XOR swizzled (wave-uniform row: no conflict) ----
#pragma unroll
    for (int r = 0; r < 16; ++r) {
      unsigned d = (unsigned)r * 4096u + sg16;
      unsigned a = d ^ (((d >> 11) & 7u) << 4);
      *(u64*)(lds + a)     = sa[r];
      *(u64*)(lds + a + 8) = sb[r];
    }
    __syncthreads();

    // ---- 16 h chunks: ds_read_b128 fragment + 4 MFMAs each ----
#pragma unroll
    for (int q = 0; q < 16; ++q) {
      int4 av = *(const int4*)(lds + ((fbase + (unsigned)q * 32u) ^ fxor));
      f16x8 a = __builtin_bit_cast(f16x8, av);
      acc[0] = __builtin_amdgcn_mfma_f32_32x32x16_f16(a, __builtin_bit_cast(f16x8, Braw[0][q]), acc[0], 0, 0, 0);
      acc[1] = __builtin_amdgcn_mfma_f32_32x32x16_f16(a, __builtin_bit_cast(f16x8, Braw[1][q]), acc[1], 0, 0, 0);
      acc[2] = __builtin_amdgcn_mfma_f32_32x32x16_f16(a, __builtin_bit_cast(f16x8, Braw[2][q]), acc[2], 0, 0, 0);
      acc[3] = __builtin_amdgcn_mfma_f32_32x32x16_f16(a, __builtin_bit_cast(f16x8, Braw[3][q]), acc[3], 0, 0, 0);
    }
    __syncthreads();  // WAR: all frag reads done before reduce overwrites buffer

    // ---- cross-wave K reduction via LDS (same 64KB buffer) ----
#pragma unroll
    for (int n = 0; n < 4; ++n) {
#pragma unroll
      for (int c = 0; c < 4; ++c) {
        float4 v;
        v.x = acc[n][4 * c + 0]; v.y = acc[n][4 * c + 1];
        v.z = acc[n][4 * c + 2]; v.w = acc[n][4 * c + 3];
        redv[((w * 4u + (unsigned)n) * 4u + (unsigned)c) * 64u + l] = v;
      }
    }
    __syncthreads();

    float gv[4][4];
#pragma unroll
    for (int n = 0; n < 4; ++n) {
      float4 s; s.x = bias_v[n]; s.y = bias_v[n]; s.z = bias_v[n]; s.w = bias_v[n];
#pragma unroll
      for (int wo = 0; wo < 4; ++wo) {
        float4 v = redv[(((unsigned)wo * 4u + (unsigned)n) * 4u + w) * 64u + l];
        s.x += v.x; s.y += v.y; s.z += v.z; s.w += v.w;
      }
      gv[n][0] = s.x; gv[n][1] = s.y; gv[n][2] = s.z; gv[n][3] = s.w;
    }

    // ---- per-lane LSTM cell update (rows 8w+i+4hi); stage h to LDS ----
    const bool last = (t == 255u);
#pragma unroll
    for (int i = 0; i < 4; ++i) {
      float ig = fast_sig(gv[0][i]);
      float fg = fast_sig(gv[1][i]);
      float gg = fast_tanh(gv[2][i]);
      float og = fast_sig(gv[3][i]);
      float cc = fg * c_st[i] + ig * gg;
      c_st[i] = cc;
      float hh = og * fast_tanh(cc);
      hst[(8u * w + (unsigned)i + 4u * hi) * 32u + lo5] = f2h(hh);
      if (last) sigh[soff[i]] = fast_sig(hh);
    }

    if (!last) {
      __syncthreads();  // h staging tile complete
      // ---- coalesced 8B agent-coherent h store-out (write-through) ----
      {
        u64 v = *(const u64*)(hst + srow * 32u + sseg * 4u);
        __hip_atomic_store((u64*)(hwr + sgoff), v, __ATOMIC_RELAXED, SCOPE_AGENT);
      }
      // prefetch next step's x fragments (independent of h; hides under drain)
      xb += 65536u;
      xr[0] = *(const int4*)(xbase + xb);
      xr[1] = *(const int4*)(xbase + xb + 32u);
      // __syncthreads lowering waits vmcnt(0): every thread's h store is ACKed
      // at the coherence point before any thread proceeds to the flag store.
      __syncthreads();
      // ---- RMW-free epoch-flag barrier ----
      if (tid == 0)
        __hip_atomic_store(&flags[cg], t + 1u, __ATOMIC_RELAXED, SCOPE_AGENT);
      if (tid < 64u) {
        const unsigned tgt = t + 1u;
        for (;;) {
          unsigned f = __hip_atomic_load(&flags[l & 31u], __ATOMIC_RELAXED, SCOPE_AGENT);
          if (__all(f >= tgt)) break;
          __builtin_amdgcn_s_sleep(1);
        }
      }
      __syncthreads();
    }

    const char* tmp = hrd; hrd = hwr; hwr = (char*)tmp;
  }
}

// out[b][o] = b_fc[o] + sum_k sigh[b][k] * W_fc[o][k]
__global__ void final_fc(const float* __restrict__ sigh, const float* __restrict__ W_fc,
                         const float* __restrict__ b_fc, float* __restrict__ out) {
  unsigned b = blockIdx.x;
  unsigned o = threadIdx.x;
  const float* hrow = sigh + (size_t)b * 1024u;
  const float* wrow = W_fc + (size_t)o * 1024u;
  float acc = b_fc[o];
#pragma unroll 8
  for (unsigned k = 0; k < 1024u; k += 4u) {
    float4 hv = *(const float4*)(hrow + k);
    float4 wv = *(const float4*)(wrow + k);
    acc += hv.x * wv.x + hv.y * wv.y + hv.z * wv.z + hv.w * wv.w;
  }
  out[b * 128u + o] = acc;
}

extern "C" void kernel_launch(void* const* d_in, const int* in_sizes, int n_in,
                              void* d_out, int out_size, void* d_ws, size_t ws_size,
                              hipStream_t stream) {
  (void)in_sizes; (void)n_in; (void)out_size; (void)ws_size;
  const float* x    = (const float*)d_in[0];
  const float* h0   = (const float*)d_in[1];
  const float* c0   = (const float*)d_in[2];
  const float* W_ih = (const float*)d_in[3];
  const float* W_hh = (const float*)d_in[4];
  const float* b_ih = (const float*)d_in[5];
  const float* b_hh = (const float*)d_in[6];
  const float* W_fc = (const float*)d_in[7];
  const float* b_fc = (const float*)d_in[8];

  char* ws = (char*)d_ws;
  unsigned short* wp   = (unsigned short*)(ws + WS_WP);
  float*          bias = (float*)(ws + WS_BIAS);
  unsigned short* xT   = (unsigned short*)(ws + WS_XT);
  unsigned short* hb0  = (unsigned short*)(ws + WS_HB0);
  unsigned short* hb1  = (unsigned short*)(ws + WS_HB1);
  float*          sigh = (float*)(ws + WS_SIGH);
  unsigned*       bar  = (unsigned*)(ws + WS_BAR);
  float*          out  = (float*)d_out;

  prep_pack<<<18432, 256, 0, stream>>>(W_ih, W_hh, b_ih, b_hh, wp, bias);
  prep_misc<<<32768, 256, 0, stream>>>(x, h0, xT, hb0, bar);
  lstm_main<<<256, 256, 67584, stream>>>(wp, bias, xT, hb0, hb1, c0, sigh, bar);
  final_fc<<<256, 128, 0, stream>>>(sigh, W_fc, b_fc, out);
}

// Round 8
// 1307.305 us; speedup vs baseline: 2.1045x; 1.0049x over previous
//
#include <hip/hip_runtime.h>

// LSTM (B=256, T=256, F=128, H=1024) + sigmoid + FC(1024->128).
// Persistent 256-WG kernel. Per step t:
//   gates[B,4H] = [h_t | x_t] (fp16) x W_cat^T (fp16, register-resident) + bias
//   per-lane i,f,g,o -> c,h update (fp32).
// R8 per-wave dataflow: wave w owns K-slice cols [w*512B) of the cohort h tile.
//  - stage: wave w loads ITS 16KB slice coalesced (rows x 512B, sc0sc1 8B pairs
//    from MALL - proven R3/R5/R7 coherence), writes its PRIVATE LDS region,
//    frag-reads only that region -> NO cross-wave barrier on the stage path
//    (same-wave DS ordering + explicit lgkmcnt(0)).
//  - barrier: per-wave poll of only its 8 producer WGs (flags cg in [8w,8w+8)).
//    Waves enter next stage independently; skew absorbed at the reduce barrier.
//  - WAR safety without full-cohort quiescence: 4 rotating h buffers.
//    At iter t a WG writes b[(t+1)&3]=b[(t-3)&3]. Any producer flag >= t
//    transitively implies ALL cohort flags >= t-1 (its 4 waves polled all 32),
//    hence all reads of h(t-3) completed. Monotonic flags, replay-safe.
// Barriers/step: 3 (reduce, hst, drain) vs 6 in R7. LDS: 64K stage + 64K
// reduce (separate -> no WAR sync) + 2K hst = 133120B.
// Tiling: WG (rg=wg>>5, cg=wg&31): rows rg*32..+31, h-cols cg*32..+31 (gate
// cols n*1024+cg*32+..). Wave w: h-K [w*256,+256) + x-K [w*32,+32).
// MFMA mfma_f32_32x32x16_f16, C: col=lane&31, row=(reg&3)+8*(reg>>2)+4*(lane>>5).

typedef _Float16 f16x8 __attribute__((ext_vector_type(8)));
typedef float f32x16 __attribute__((ext_vector_type(16)));
typedef unsigned long long u64;

#define SCOPE_AGENT __HIP_MEMORY_SCOPE_AGENT

#define WS_WP    0ull
#define WS_BIAS  9437184ull
#define WS_XT    (WS_BIAS + 16384ull)
#define WS_HB    (WS_XT + 16777216ull)          // 4 buffers x 524288B
#define WS_SIGH  (WS_HB + 4ull * 524288ull)
#define WS_BAR   (WS_SIGH + 1048576ull)

__device__ __forceinline__ unsigned short f2h(float f) {
  _Float16 h = (_Float16)f;
  return __builtin_bit_cast(unsigned short, h);
}

__device__ __forceinline__ float fast_sig(float x) {
  return __builtin_amdgcn_rcpf(1.f + __expf(-x));
}
__device__ __forceinline__ float fast_tanh(float x) {
  // tanh(x) = 2*sigmoid(2x) - 1 ; exp overflow -> rcp(inf)=0 -> -1 (correct)
  return __builtin_fmaf(2.f, fast_sig(2.f * x), -1.f);
}

// Pack W_cat[4096][1152] (fp16) into per-(cg,wave,n,q,lane) MFMA B-fragments.
// flat idx i = ((((cg*4 + w)*4 + n)*18 + q)*64 + l)*8 + j
//   gcol = n*1024 + cg*32 + (l&31)
//   q<16:  k = w*256 + q*16 + (l>>5)*8 + j          (h region, W_hh[gcol][k])
//   q>=16: f = w*32 + (q-16)*16 + (l>>5)*8 + j      (x region, W_ih[gcol][f])
__global__ void prep_pack(const float* __restrict__ W_ih, const float* __restrict__ W_hh,
                          const float* __restrict__ b_ih, const float* __restrict__ b_hh,
                          unsigned short* __restrict__ wp, float* __restrict__ bias) {
  unsigned i = blockIdx.x * 256u + threadIdx.x;
  if (i < 4718592u) {
    unsigned j = i & 7u;
    unsigned l = (i >> 3) & 63u;
    unsigned rest = i >> 9;
    unsigned q = rest % 18u;
    unsigned rest2 = rest / 18u;
    unsigned n = rest2 & 3u;
    unsigned rest3 = rest2 >> 2;
    unsigned w = rest3 & 3u;
    unsigned cg = rest3 >> 2;
    unsigned gcol = n * 1024u + cg * 32u + (l & 31u);
    unsigned khi = (l >> 5) * 8u + j;
    float v;
    if (q < 16u) {
      unsigned k = w * 256u + q * 16u + khi;
      v = W_hh[(size_t)gcol * 1024u + k];
    } else {
      unsigned k = w * 32u + (q - 16u) * 16u + khi;
      v = W_ih[(size_t)gcol * 128u + k];
    }
    wp[i] = f2h(v);
  }
  if (i < 4096u) bias[i] = b_ih[i] + b_hh[i];
}

// x[B][T][F] fp32 -> xT[T][B][F] fp16 ; h0 -> fp16 hb buffer 0 ; zero flags.
__global__ void prep_misc(const float* __restrict__ x, const float* __restrict__ h0,
                          unsigned short* __restrict__ xT, unsigned short* __restrict__ hb0,
                          unsigned* __restrict__ bar) {
  unsigned i = blockIdx.x * 256u + threadIdx.x;
  if (i < 8388608u) {
    unsigned f = i & 127u;
    unsigned b = (i >> 7) & 255u;
    unsigned t = i >> 15;
    xT[i] = f2h(x[((size_t)b * 256u + t) * 128u + f]);
  }
  if (i < 262144u) hb0[i] = f2h(h0[i]);
  if (i < 768u) bar[i] = 0u;
}

__launch_bounds__(256, 1)
__global__ void lstm_main(const unsigned short* __restrict__ wp,
                          const float* __restrict__ bias,
                          const unsigned short* __restrict__ xT,
                          unsigned short* __restrict__ hb,
                          const float* __restrict__ c0,
                          float* __restrict__ sigh,
                          unsigned* __restrict__ bar) {
  extern __shared__ char lds[];
  // [0,64K): per-wave h stage, region w*16KB, [row][512B], XOR-swizzled
  // [64K,128K): f32 cross-wave reduce   [128K,+2K): hst h staging tile
  float4* redv = (float4*)(lds + 65536);
  unsigned short* hst = (unsigned short*)(lds + 131072);

  const unsigned tid = threadIdx.x;
  const unsigned wg  = blockIdx.x;
  const unsigned w   = tid >> 6;       // wave 0..3 (K-slice owner)
  const unsigned l   = tid & 63u;
  const unsigned rg  = wg >> 5;        // 0..7  batch row group = cohort
  const unsigned cg  = wg & 31u;       // 0..31 h-col group
  const unsigned lo5 = l & 31u;
  const unsigned hi  = l >> 5;

  // ---- register-resident W fragments (72 x int4 = 288 regs) ----
  int4 Braw[4][18];
  {
    const int4* wpv = (const int4*)wp;
    const unsigned wbase = (cg * 4u + w) * 4608u;
#pragma unroll
    for (int n = 0; n < 4; ++n) {
#pragma unroll
      for (int q = 0; q < 18; ++q) {
        Braw[n][q] = wpv[wbase + (unsigned)(n * 18 + q) * 64u + l];
      }
    }
  }

  float bias_v[4];
#pragma unroll
  for (int n = 0; n < 4; ++n) bias_v[n] = bias[(unsigned)n * 1024u + cg * 32u + lo5];

  // c state + output offsets: rows r = rg*32 + 8w + i + 4*hi, col = cg*32 + lo5
  const unsigned col = cg * 32u + lo5;
  float c_st[4];
  unsigned soff[4];
#pragma unroll
  for (int i = 0; i < 4; ++i) {
    unsigned r = rg * 32u + 8u * w + (unsigned)i + 4u * hi;
    soff[i] = r * 1024u + col;
    c_st[i] = c0[soff[i]];
  }

  // stage: wave w loads rows (2r+hi) bytes [w*512 + lo5*16) of the cohort tile
  const unsigned sgsrc0 = (rg * 32u + hi) * 2048u + w * 512u + lo5 * 16u;  // + r*4096
  const unsigned sdst0  = w * 16384u + hi * 512u + lo5 * 16u;              // + r*1024
  // frag read: region w, row lo5, kbyte q*32 + hi*16
  const unsigned fbase = w * 16384u + lo5 * 512u + hi * 16u;
  const unsigned fxor  = (lo5 & 7u) << 4;

  unsigned xb = ((rg * 32u + lo5) * 128u + w * 32u + hi * 8u) * 2u;  // +65536/step

  const char* xbase = (const char*)xT;
  const char* hbase = (const char*)hb;
  unsigned* flags = &bar[rg * 32u];    // 32 x 4B epoch flags, one 128B line

  // h store-out: 256 threads x 8B, rows rg*32+(tid>>3), col bytes cg*64+(tid&7)*8
  const unsigned srow = tid >> 3;
  const unsigned sseg = tid & 7u;
  const unsigned sgoff = (((rg * 32u + srow) * 1024u) + cg * 32u + sseg * 4u) * 2u;

  int4 xr[2];
  xr[0] = *(const int4*)(xbase + xb);
  xr[1] = *(const int4*)(xbase + xb + 32u);

  for (unsigned t = 0; t < 256u; ++t) {
    const char* hrd = hbase + ((t & 3u) * 524288u);
    char* hwr = (char*)hbase + (((t + 1u) & 3u) * 524288u);

    // ---- per-wave coalesced stage loads (sc0sc1 -> MALL), 16KB slice ----
    u64 sa[16], sb[16];
#pragma unroll
    for (int r = 0; r < 16; ++r) {
      const char* src = hrd + sgsrc0 + (unsigned)r * 4096u;
      sa[r] = __hip_atomic_load((const u64*)src,       __ATOMIC_RELAXED, SCOPE_AGENT);
      sb[r] = __hip_atomic_load((const u64*)(src + 8), __ATOMIC_RELAXED, SCOPE_AGENT);
    }

    f32x16 acc[4] = {};
    // x chunks while stage loads are in flight
#pragma unroll
    for (int qx = 0; qx < 2; ++qx) {
      f16x8 a = __builtin_bit_cast(f16x8, xr[qx]);
      acc[0] = __builtin_amdgcn_mfma_f32_32x32x16_f16(a, __builtin_bit_cast(f16x8, Braw[0][16 + qx]), acc[0], 0, 0, 0);
      acc[1] = __builtin_amdgcn_mfma_f32_32x32x16_f16(a, __builtin_bit_cast(f16x8, Braw[1][16 + qx]), acc[1], 0, 0, 0);
      acc[2] = __builtin_amdgcn_mfma_f32_32x32x16_f16(a, __builtin_bit_cast(f16x8, Braw[2][16 + qx]), acc[2], 0, 0, 0);
      acc[3] = __builtin_amdgcn_mfma_f32_32x32x16_f16(a, __builtin_bit_cast(f16x8, Braw[3][16 + qx]), acc[3], 0, 0, 0);
    }

    // ---- write own slice to own LDS region (XOR swizzle by row&7) ----
#pragma unroll
    for (int r = 0; r < 16; ++r) {
      unsigned d = sdst0 + (unsigned)r * 1024u;
      unsigned a = d ^ (((d >> 9) & 7u) << 4);
      struct { u64 a, b; } p = { sa[r], sb[r] };
      *(int4*)(lds + a) = __builtin_bit_cast(int4, p);
    }
    // same-wave DS write->read ordering (no cross-wave consumer of this region)
    asm volatile("s_waitcnt lgkmcnt(0)" ::: "memory");

    // ---- 16 h chunks from OWN region: ds_read_b128 + 4 MFMAs each ----
#pragma unroll
    for (int q = 0; q < 16; ++q) {
      int4 av = *(const int4*)(lds + ((fbase + (unsigned)q * 32u) ^ fxor));
      f16x8 a = __builtin_bit_cast(f16x8, av);
      acc[0] = __builtin_amdgcn_mfma_f32_32x32x16_f16(a, __builtin_bit_cast(f16x8, Braw[0][q]), acc[0], 0, 0, 0);
      acc[1] = __builtin_amdgcn_mfma_f32_32x32x16_f16(a, __builtin_bit_cast(f16x8, Braw[1][q]), acc[1], 0, 0, 0);
      acc[2] = __builtin_amdgcn_mfma_f32_32x32x16_f16(a, __builtin_bit_cast(f16x8, Braw[2][q]), acc[2], 0, 0, 0);
      acc[3] = __builtin_amdgcn_mfma_f32_32x32x16_f16(a, __builtin_bit_cast(f16x8, Braw[3][q]), acc[3], 0, 0, 0);
    }

    // ---- cross-wave K reduction (separate 64KB buffer) ----
#pragma unroll
    for (int n = 0; n < 4; ++n) {
#pragma unroll
      for (int c = 0; c < 4; ++c) {
        float4 v;
        v.x = acc[n][4 * c + 0]; v.y = acc[n][4 * c + 1];
        v.z = acc[n][4 * c + 2]; v.w = acc[n][4 * c + 3];
        redv[((w * 4u + (unsigned)n) * 4u + (unsigned)c) * 64u + l] = v;
      }
    }
    __syncthreads();  // reduce buffer complete

    float gv[4][4];
#pragma unroll
    for (int n = 0; n < 4; ++n) {
      float4 s; s.x = bias_v[n]; s.y = bias_v[n]; s.z = bias_v[n]; s.w = bias_v[n];
#pragma unroll
      for (int wo = 0; wo < 4; ++wo) {
        float4 v = redv[(((unsigned)wo * 4u + (unsigned)n) * 4u + w) * 64u + l];
        s.x += v.x; s.y += v.y; s.z += v.z; s.w += v.w;
      }
      gv[n][0] = s.x; gv[n][1] = s.y; gv[n][2] = s.z; gv[n][3] = s.w;
    }

    // ---- per-lane LSTM cell update (rows 8w+i+4hi); stage h to LDS ----
    const bool last = (t == 255u);
#pragma unroll
    for (int i = 0; i < 4; ++i) {
      float ig = fast_sig(gv[0][i]);
      float fg = fast_sig(gv[1][i]);
      float gg = fast_tanh(gv[2][i]);
      float og = fast_sig(gv[3][i]);
      float cc = fg * c_st[i] + ig * gg;
      c_st[i] = cc;
      float hh = og * fast_tanh(cc);
      hst[(8u * w + (unsigned)i + 4u * hi) * 32u + lo5] = f2h(hh);
      if (last) sigh[soff[i]] = fast_sig(hh);
    }

    if (!last) {
      __syncthreads();  // hst tile complete
      // ---- coalesced 8B agent-coherent h store-out (write-through) ----
      {
        u64 v = *(const u64*)(hst + srow * 32u + sseg * 4u);
        __hip_atomic_store((u64*)(hwr + sgoff), v, __ATOMIC_RELAXED, SCOPE_AGENT);
      }
      // prefetch next step's x fragments
      xb += 65536u;
      xr[0] = *(const int4*)(xbase + xb);
      xr[1] = *(const int4*)(xbase + xb + 32u);
      // barrier lowering waits vmcnt(0): all threads' h stores ACKed at MALL
      __syncthreads();
      if (tid == 0)
        __hip_atomic_store(&flags[cg], t + 1u, __ATOMIC_RELAXED, SCOPE_AGENT);
      // ---- per-wave poll: only this wave's 8 producer WGs ----
      {
        const unsigned tgt = t + 1u;
        const unsigned fidx = w * 8u + (l & 7u);
        for (;;) {
          unsigned f = __hip_atomic_load(&flags[fidx], __ATOMIC_RELAXED, SCOPE_AGENT);
          if (__all(l >= 8u || f >= tgt)) break;
          __builtin_amdgcn_s_sleep(1);
        }
      }
      // no barrier: waves proceed to next stage independently
    }
  }
}

// out[b][o] = b_fc[o] + sum_k sigh[b][k] * W_fc[o][k]
__global__ void final_fc(const float* __restrict__ sigh, const float* __restrict__ W_fc,
                         const float* __restrict__ b_fc, float* __restrict__ out) {
  unsigned b = blockIdx.x;
  unsigned o = threadIdx.x;
  const float* hrow = sigh + (size_t)b * 1024u;
  const float* wrow = W_fc + (size_t)o * 1024u;
  float acc = b_fc[o];
#pragma unroll 8
  for (unsigned k = 0; k < 1024u; k += 4u) {
    float4 hv = *(const float4*)(hrow + k);
    float4 wv = *(const float4*)(wrow + k);
    acc += hv.x * wv.x + hv.y * wv.y + hv.z * wv.z + hv.w * wv.w;
  }
  out[b * 128u + o] = acc;
}

extern "C" void kernel_launch(void* const* d_in, const int* in_sizes, int n_in,
                              void* d_out, int out_size, void* d_ws, size_t ws_size,
                              hipStream_t stream) {
  (void)in_sizes; (void)n_in; (void)out_size; (void)ws_size;
  const float* x    = (const float*)d_in[0];
  const float* h0   = (const float*)d_in[1];
  const float* c0   = (const float*)d_in[2];
  const float* W_ih = (const float*)d_in[3];
  const float* W_hh = (const float*)d_in[4];
  const float* b_ih = (const float*)d_in[5];
  const float* b_hh = (const float*)d_in[6];
  const float* W_fc = (const float*)d_in[7];
  const float* b_fc = (const float*)d_in[8];

  char* ws = (char*)d_ws;
  unsigned short* wp   = (unsigned short*)(ws + WS_WP);
  float*          bias = (float*)(ws + WS_BIAS);
  unsigned short* xT   = (unsigned short*)(ws + WS_XT);
  unsigned short* hb   = (unsigned short*)(ws + WS_HB);
  float*          sigh = (float*)(ws + WS_SIGH);
  unsigned*       bar  = (unsigned*)(ws + WS_BAR);
  float*          out  = (float*)d_out;

  prep_pack<<<18432, 256, 0, stream>>>(W_ih, W_hh, b_ih, b_hh, wp, bias);
  prep_misc<<<32768, 256, 0, stream>>>(x, h0, xT, hb, bar);
  lstm_main<<<256, 256, 133120, stream>>>(wp, bias, xT, hb, c0, sigh, bar);
  final_fc<<<256, 128, 0, stream>>>(sigh, W_fc, b_fc, out);
}